// Round 4
// baseline (317.678 us; speedup 1.0000x reference)
//
#include <hip/hip_runtime.h>
#include <hip/hip_bf16.h>

#define SEQ 2048
#define DIM 128
#define NBH 32
#define NROWS (NBH*SEQ)      // 65536
#define NBLK (NROWS/32)      // 2048
#define SCALE 0.08838834764831845f  // 1/sqrt(128)
#define QSC (0.08838834764831845f * 1.4426950408889634f)  // SCALE*log2(e): exp2(s') == exp(s*SCALE)

typedef __attribute__((ext_vector_type(8))) short short8;
typedef __attribute__((ext_vector_type(16))) float float16;

__device__ __forceinline__ unsigned short f2bf(float x) {
    union { float f; unsigned u; } v; v.f = x;
    unsigned r = v.u + 0x7fffu + ((v.u >> 16) & 1u);   // RNE
    return (unsigned short)(r >> 16);
}
__device__ __forceinline__ unsigned pack_bf16(float a, float b) {
    float2 f; f.x = a; f.y = b;
    __hip_bfloat162 h = __float22bfloat162_rn(f);
    union { __hip_bfloat162 h2; unsigned u; } cv; cv.h2 = h; return cv.u;
}
__device__ __forceinline__ void gl_lds16(const void* g, void* l) {
    __builtin_amdgcn_global_load_lds((const __attribute__((address_space(1))) unsigned int*)g,
                                     (__attribute__((address_space(3))) unsigned int*)l, 16, 0, 0);
}

// ---------------- LSH hash: PERM[code] == code ^ (code>>1)
// 4 rows per wave: 16-lane groups, 8 d-elements per lane, proj slice held in regs.
__global__ __launch_bounds__(256) void hash_kernel(const float* __restrict__ qg, const float* __restrict__ kg,
                            const float* __restrict__ proj,
                            int* __restrict__ qh, int* __restrict__ kh)
{
    const int gw   = (int)((blockIdx.x * blockDim.x + threadIdx.x) >> 6);
    const int lane = threadIdx.x & 63;
    const int sub  = lane >> 4;            // row-in-group 0..3
    const int dl   = (lane & 15) * 8;      // d-chunk base
    const int r    = gw * 4 + sub;
    const float* src; int* dst; int row;
    if (r < NROWS) { src = qg; dst = qh; row = r; }
    else           { src = kg; dst = kh; row = r - NROWS; }

    const float* x = src + (size_t)row * DIM + dl;
    float xv[8];
    {
        float4 f0 = *(const float4*)x;
        float4 f1 = *(const float4*)(x + 4);
        xv[0]=f0.x; xv[1]=f0.y; xv[2]=f0.z; xv[3]=f0.w;
        xv[4]=f1.x; xv[5]=f1.y; xv[6]=f1.z; xv[7]=f1.w;
    }
    float pj[56];
    #pragma unroll
    for (int i = 0; i < 14; ++i)
        *(float4*)&pj[i*4] = *(const float4*)(proj + dl*7 + i*4);

    float a[7] = {0.f,0.f,0.f,0.f,0.f,0.f,0.f};
    #pragma unroll
    for (int d = 0; d < 8; ++d)
        #pragma unroll
        for (int p = 0; p < 7; ++p) a[p] = fmaf(xv[d], pj[d*7+p], a[p]);

    #pragma unroll
    for (int off = 1; off < 16; off <<= 1)
        #pragma unroll
        for (int p = 0; p < 7; ++p) a[p] += __shfl_xor(a[p], off, 64);

    if ((lane & 15) == 0) {
        int code = 0;
        if (a[0] > 0.f) code |= 1;  if (a[1] > 0.f) code |= 2;
        if (a[2] > 0.f) code |= 4;  if (a[3] > 0.f) code |= 8;
        if (a[4] > 0.f) code |= 16; if (a[5] > 0.f) code |= 32;
        if (a[6] > 0.f) code |= 64;
        dst[row] = code ^ (code >> 1);
    }
}

// ---------------- parallel stable counting sort per (b,h)
__global__ __launch_bounds__(256) void sort_kernel(const int* __restrict__ qh,
                                                   int* __restrict__ sidx, int* __restrict__ qhs)
{
    __shared__ unsigned short cnt[128][260];
    __shared__ int startv[128];
    const int bh = blockIdx.x;
    const int t  = threadIdx.x;
    const int base = bh*SEQ;

    for (int i = t; i < 128*260; i += 256) ((unsigned short*)cnt)[i] = 0;
    __syncthreads();

    int hv[8];
    {
        int4 a = *(const int4*)(qh + base + t*8);
        int4 b = *(const int4*)(qh + base + t*8 + 4);
        hv[0]=a.x; hv[1]=a.y; hv[2]=a.z; hv[3]=a.w;
        hv[4]=b.x; hv[5]=b.y; hv[6]=b.z; hv[7]=b.w;
    }
    #pragma unroll
    for (int i = 0; i < 8; ++i) cnt[hv[i]][t]++;
    __syncthreads();

    // per-value exclusive column prefix: wave wv handles values wv, wv+4, ...
    const int wv = t >> 6, l = t & 63;
    #pragma unroll 1
    for (int v = wv; v < 128; v += 4) {
        ushort4 cc = *(const ushort4*)&cnt[v][4*l];
        unsigned c0 = cc.x, c1 = cc.y, c2 = cc.z, c3 = cc.w;
        unsigned s01 = c0 + c1;
        unsigned s = s01 + c2 + c3;
        unsigned inc = s;
        #pragma unroll
        for (int off = 1; off < 64; off <<= 1) {
            unsigned o = __shfl_up(inc, off, 64);
            if (l >= off) inc += o;
        }
        unsigned ex = inc - s;
        ushort4 wb;
        wb.x = (unsigned short)ex;
        wb.y = (unsigned short)(ex + c0);
        wb.z = (unsigned short)(ex + s01);
        wb.w = (unsigned short)(ex + s01 + c2);
        *(ushort4*)&cnt[v][4*l] = wb;
        if (l == 63) cnt[v][256] = (unsigned short)inc;   // total count of v
    }
    __syncthreads();

    // exclusive prefix over the 128 per-value totals (wave 0, 2 values/lane)
    if (t < 64) {
        int a0 = cnt[2*t][256], a1 = cnt[2*t+1][256];
        int s2 = a0 + a1, inc = s2;
        #pragma unroll
        for (int off = 1; off < 64; off <<= 1) {
            int o = __shfl_up(inc, off, 64);
            if (t >= off) inc += o;
        }
        int ex = inc - s2;
        startv[2*t]   = ex;
        startv[2*t+1] = ex + a0;
    }
    __syncthreads();

    #pragma unroll
    for (int i = 0; i < 8; ++i) {
        const int v = hv[i];
        int prior = 0;
        #pragma unroll
        for (int j = 0; j < 8; ++j) if (j < i && hv[j] == v) ++prior;
        const int rank = startv[v] + (int)cnt[v][t] + prior;
        sidx[base + rank] = t*8 + i;
        qhs[base + rank]  = v;
    }
}

// ---------------- prep: K -> bf16 row-major; V -> bf16 transposed [h][d][key]
__global__ __launch_bounds__(256) void prep_kernel(const float* __restrict__ kg,
                                                   const float* __restrict__ vg,
                                                   unsigned short* __restrict__ kbf,
                                                   unsigned short* __restrict__ vtg)
{
    __shared__ unsigned short T[128][72];
    const int t  = threadIdx.x;
    const int h  = blockIdx.x >> 5;
    const int sl = blockIdx.x & 31;
    const size_t base = ((size_t)h*SEQ + sl*64) * DIM;

    #pragma unroll
    for (int i = 0; i < 8; ++i) {
        const float4 f = *(const float4*)(kg + base + ((size_t)i*256 + t)*4);
        uint2 pk; pk.x = pack_bf16(f.x, f.y); pk.y = pack_bf16(f.z, f.w);
        *(uint2*)(kbf + base + ((size_t)i*256 + t)*4) = pk;
    }

    const int kk = t & 63, seg = t >> 6;
    #pragma unroll
    for (int i = 0; i < 8; ++i) {
        float4 f = *(const float4*)(vg + base + (size_t)kk*DIM + seg*32 + i*4);
        T[seg*32 + i*4 + 0][kk] = f2bf(f.x);
        T[seg*32 + i*4 + 1][kk] = f2bf(f.y);
        T[seg*32 + i*4 + 2][kk] = f2bf(f.z);
        T[seg*32 + i*4 + 3][kk] = f2bf(f.w);
    }
    __syncthreads();
    const int r = t >> 1, hf = t & 1;
    unsigned short* dst = vtg + ((size_t)h*DIM + r)*SEQ + sl*64 + hf*32;
    #pragma unroll
    for (int i = 0; i < 4; ++i)
        *(short8*)(dst + i*8) = *(const short8*)&T[r][hf*32 + i*8];
}

// ---------------- dense flash attention: bf16 MFMA, double-buffered LDS staging.
// STRUCTURAL change this round: 64 q-rows per wave (2 Q-frag sets A/B, 2 accumulator
// sets) so every ds_read_b128 of K/V feeds TWO MFMAs -> LDS-reads-per-MFMA halved
// (LDS pipe was 45% of the CU at 32 q/wave; MfmaUtil pinned at ~30% across 3 schedule
// variants proved the pipe budget, not the schedule, was the limit). Block covers 256
// q-rows; grid 256 = 1 block/CU, 1 wave/SIMD; __launch_bounds__(256,1) allows ~290 VGPR.
// Latency hidden by ILP: 2 independent QK chains + 8 independent PV chains per wave.
__global__ __launch_bounds__(256, 1) void dense_attn_mfma(
    const unsigned short* __restrict__ kbf, const unsigned short* __restrict__ vtg,
    const float* __restrict__ qg, float* __restrict__ outg)
{
    __shared__ __align__(16) unsigned short KbF[2*8192];   // [buf][key(64) x d(128)]
    __shared__ __align__(16) unsigned short VbF[2*8192];   // [buf][d(128) x key(64)]

    const int t    = threadIdx.x;
    const int lane = t & 63;
    const int w    = t >> 6;
    const int q5   = lane >> 5;
    const int l31  = lane & 31;
    const int e    = l31 & 7;

    const int b    = blockIdx.x;              // 256 blocks
    const int head = (b & 7) * 4 + (b >> 6);  // same head -> same b&7 -> same XCD
    const int qblk = (b >> 3) & 7;            // 256-row q block

    const float* Qg = qg + ((size_t)head*SEQ + qblk*256 + w*64) * DIM;
    const unsigned short* Kh = kbf + (size_t)head*SEQ*DIM;
    const unsigned short* Vh = vtg + (size_t)head*DIM*SEQ;

    // ---- kt-invariant LDS read offsets (shorts), swizzle baked in
    int koff[8], voff[4];
    #pragma unroll
    for (int ch = 0; ch < 8; ++ch) koff[ch] = l31*128 + (((2*ch + q5) ^ e) * 8);
    #pragma unroll
    for (int u = 0; u < 4; ++u)    voff[u]  = l31*64  + ((((u>>1)*4 + (u&1)*2 + q5) ^ e) * 8);

    // ---- kt-invariant staging pointers (advance by const per tile)
    const unsigned short* kgp[4]; unsigned short* kls[4];
    const unsigned short* vgp[4]; unsigned short* vls[4];
    #pragma unroll
    for (int i = 0; i < 4; ++i) {
        const int j = w*4 + i;
        const int r = j*4 + (lane >> 4);
        const int u = (lane & 15) ^ (r & 7);
        kgp[i] = Kh + r*DIM + u*8;            // += 8192 per tile
        kls[i] = KbF + j*512;
        const int d = j*8 + (lane >> 3);
        const int u2 = (lane & 7) ^ (d & 7);
        vgp[i] = Vh + (size_t)d*SEQ + u2*8;   // += 64 per tile
        vls[i] = VbF + j*512;
    }

    auto stage = [&](const int buf) {
        #pragma unroll
        for (int i = 0; i < 4; ++i) gl_lds16(kgp[i], kls[i] + buf*8192);
        #pragma unroll
        for (int i = 0; i < 4; ++i) gl_lds16(vgp[i], vls[i] + buf*8192);
        #pragma unroll
        for (int i = 0; i < 4; ++i) { kgp[i] += 8192; vgp[i] += 64; }
    };

    stage(0);   // tile 0 DMA overlaps Q-frag load/pack below

    // ---- Q frags (B-operand), two 32-row halves, pre-scaled by SCALE*log2e
    union FR { unsigned u[4]; short8 s; };
    short8 QfA[8], QfB[8];
    #pragma unroll
    for (int ch = 0; ch < 8; ++ch) {
        const float* pA = Qg + (size_t)l31*DIM + ch*16 + q5*8;
        const float* pB = pA + (size_t)32*DIM;
        float4 a0 = *(const float4*)pA;
        float4 a1 = *(const float4*)(pA + 4);
        float4 b0 = *(const float4*)pB;
        float4 b1 = *(const float4*)(pB + 4);
        FR fa, fb;
        fa.u[0] = pack_bf16(a0.x*QSC, a0.y*QSC);
        fa.u[1] = pack_bf16(a0.z*QSC, a0.w*QSC);
        fa.u[2] = pack_bf16(a1.x*QSC, a1.y*QSC);
        fa.u[3] = pack_bf16(a1.z*QSC, a1.w*QSC);
        fb.u[0] = pack_bf16(b0.x*QSC, b0.y*QSC);
        fb.u[1] = pack_bf16(b0.z*QSC, b0.w*QSC);
        fb.u[2] = pack_bf16(b1.x*QSC, b1.y*QSC);
        fb.u[3] = pack_bf16(b1.z*QSC, b1.w*QSC);
        QfA[ch] = fa.s;
        QfB[ch] = fb.s;
    }

    float16 oA[4], oB[4];
    #pragma unroll
    for (int mt = 0; mt < 4; ++mt)
        #pragma unroll
        for (int r = 0; r < 16; ++r) { oA[mt][r] = 0.f; oB[mt][r] = 0.f; }
    float lsumA = 0.f, lsumB = 0.f;

    auto body = [&](const int buf) {
        #pragma unroll
        for (int s = 0; s < 2; ++s) {
            float16 svA, svB;
            #pragma unroll
            for (int r = 0; r < 16; ++r) { svA[r] = 0.f; svB[r] = 0.f; }
            __builtin_amdgcn_s_setprio(1);
            #pragma unroll
            for (int ch = 0; ch < 8; ++ch) {
                short8 kf = *(const short8*)&KbF[buf*8192 + s*4096 + koff[ch]];
                svA = __builtin_amdgcn_mfma_f32_32x32x16_bf16(kf, QfA[ch], svA, 0, 0, 0);
                svB = __builtin_amdgcn_mfma_f32_32x32x16_bf16(kf, QfB[ch], svB, 0, 0, 0);
            }
            __builtin_amdgcn_s_setprio(0);
            unsigned pkA[8], pkB[8];
            #pragma unroll
            for (int rp = 0; rp < 8; ++rp) {
                float a0 = __builtin_amdgcn_exp2f(svA[2*rp]);
                float a1 = __builtin_amdgcn_exp2f(svA[2*rp+1]);
                float b0 = __builtin_amdgcn_exp2f(svB[2*rp]);
                float b1 = __builtin_amdgcn_exp2f(svB[2*rp+1]);
                lsumA += a0 + a1;
                lsumB += b0 + b1;
                pkA[rp] = pack_bf16(a0, a1);
                pkB[rp] = pack_bf16(b0, b1);
            }
            unsigned eA0 = __shfl_xor(q5 ? pkA[0] : pkA[2], 32, 64);
            unsigned eA1 = __shfl_xor(q5 ? pkA[1] : pkA[3], 32, 64);
            unsigned eA2 = __shfl_xor(q5 ? pkA[4] : pkA[6], 32, 64);
            unsigned eA3 = __shfl_xor(q5 ? pkA[5] : pkA[7], 32, 64);
            unsigned eB0 = __shfl_xor(q5 ? pkB[0] : pkB[2], 32, 64);
            unsigned eB1 = __shfl_xor(q5 ? pkB[1] : pkB[3], 32, 64);
            unsigned eB2 = __shfl_xor(q5 ? pkB[4] : pkB[6], 32, 64);
            unsigned eB3 = __shfl_xor(q5 ? pkB[5] : pkB[7], 32, 64);
            FR cA0, cA1, cB0, cB1;
            if (q5 == 0) {
                cA0.u[0]=pkA[0]; cA0.u[1]=pkA[1]; cA0.u[2]=eA0;    cA0.u[3]=eA1;
                cA1.u[0]=pkA[4]; cA1.u[1]=pkA[5]; cA1.u[2]=eA2;    cA1.u[3]=eA3;
                cB0.u[0]=pkB[0]; cB0.u[1]=pkB[1]; cB0.u[2]=eB0;    cB0.u[3]=eB1;
                cB1.u[0]=pkB[4]; cB1.u[1]=pkB[5]; cB1.u[2]=eB2;    cB1.u[3]=eB3;
            } else {
                cA0.u[0]=eA0;    cA0.u[1]=eA1;    cA0.u[2]=pkA[2]; cA0.u[3]=pkA[3];
                cA1.u[0]=eA2;    cA1.u[1]=eA3;    cA1.u[2]=pkA[6]; cA1.u[3]=pkA[7];
                cB0.u[0]=eB0;    cB0.u[1]=eB1;    cB0.u[2]=pkB[2]; cB0.u[3]=pkB[3];
                cB1.u[0]=eB2;    cB1.u[1]=eB3;    cB1.u[2]=pkB[6]; cB1.u[3]=pkB[7];
            }
            __builtin_amdgcn_s_setprio(1);
            #pragma unroll
            for (int c = 0; c < 2; ++c) {
                short8 pfA = c ? cA1.s : cA0.s;
                short8 pfB = c ? cB1.s : cB0.s;
                #pragma unroll
                for (int mt = 0; mt < 4; ++mt) {
                    short8 vf = *(const short8*)&VbF[buf*8192 + mt*2048 + voff[s*2 + c]];
                    oA[mt] = __builtin_amdgcn_mfma_f32_32x32x16_bf16(vf, pfA, oA[mt], 0, 0, 0);
                    oB[mt] = __builtin_amdgcn_mfma_f32_32x32x16_bf16(vf, pfB, oB[mt], 0, 0, 0);
                }
            }
            __builtin_amdgcn_s_setprio(0);
        }
    };

    // Double-buffered schedule (plain __syncthreads: drains vmcnt+lgkmcnt, which at
    // a full-body lead time is already satisfied; measured best across 3 variants).
    #pragma unroll 1
    for (int kt2 = 0; kt2 < 16; ++kt2) {
        __syncthreads();                    // buf0 (tile 2*kt2) ready
        stage(1);                           // tile 2*kt2+1 -> buf1
        body(0);                            // consume tile 2*kt2
        __syncthreads();                    // buf1 ready; buf0 reads done
        if (kt2 < 15) stage(0);             // tile 2*kt2+2 -> buf0
        body(1);                            // consume tile 2*kt2+1
    }

    const float lA = lsumA + __shfl_xor(lsumA, 32, 64);
    const float lB = lsumB + __shfl_xor(lsumB, 32, 64);
    const float invA = 1.f / lA;
    const float invB = 1.f / lB;
    float* orowA = outg + ((size_t)head*SEQ + qblk*256 + w*64 + l31) * DIM;
    float* orowB = orowA + (size_t)32*DIM;
    #pragma unroll
    for (int mt = 0; mt < 4; ++mt)
        #pragma unroll
        for (int rg = 0; rg < 4; ++rg) {
            const int d0 = mt*32 + rg*8 + q5*4;
            float4 oa, ob;
            oa.x = oA[mt][rg*4+0]*invA; oa.y = oA[mt][rg*4+1]*invA;
            oa.z = oA[mt][rg*4+2]*invA; oa.w = oA[mt][rg*4+3]*invA;
            ob.x = oB[mt][rg*4+0]*invB; ob.y = oB[mt][rg*4+1]*invB;
            ob.z = oB[mt][rg*4+2]*invB; ob.w = oB[mt][rg*4+3]*invB;
            *(float4*)(orowA + d0) = oa;
            *(float4*)(orowB + d0) = ob;
        }
}

// ---------------- blocked critical attention + MSE loss: one wave per 32-block,
// bf16 MFMA, fp32 accum, ZERO LDS. criticality fused in via ballot on kh==qhs.
__global__ __launch_bounds__(256) void crit_attn(
    const unsigned short* __restrict__ kbf, const unsigned short* __restrict__ vtg,
    const float* __restrict__ qg, const int* __restrict__ sidx,
    const int* __restrict__ kh, const int* __restrict__ qhs,
    const float* __restrict__ outg, float* __restrict__ lossp)
{
    __shared__ float wsum[4];
    const int t    = threadIdx.x;
    const int lane = t & 63;
    const int w    = t >> 6;
    const int nb   = blockIdx.x * 4 + w;          // 0..2047
    const int q5   = lane >> 5;
    const int l31  = lane & 31;
    const int bh   = nb >> 6;

    // ---- fused criticality: keep = 1 iff zero hash matches in this 32-block
    const int khv = kh[nb*32 + l31];
    const int qhv = qhs[nb*32 + l31];
    const unsigned long long mm = __ballot(khv == qhv);
    const float kp = ((mm & 0xffffffffull) == 0ull) ? 1.0f : 0.0f;

    const int qrow = sidx[bh*SEQ + (nb & 63)*32 + l31];

    // ---- Q frags (B-operand), gathered rows, pre-scaled by SCALE*log2e
    union FR { unsigned u[4]; short8 s; };
    short8 Qf[8];
    const float* Qg = qg + ((size_t)bh*SEQ + qrow) * DIM;
    #pragma unroll
    for (int ch = 0; ch < 8; ++ch) {
        const float* p = Qg + ch*16 + q5*8;
        float4 f0 = *(const float4*)p;
        float4 f1 = *(const float4*)(p + 4);
        FR fr;
        fr.u[0] = pack_bf16(f0.x*QSC, f0.y*QSC);
        fr.u[1] = pack_bf16(f0.z*QSC, f0.w*QSC);
        fr.u[2] = pack_bf16(f1.x*QSC, f1.y*QSC);
        fr.u[3] = pack_bf16(f1.z*QSC, f1.w*QSC);
        Qf[ch] = fr.s;
    }

    // ---- QK^T: S[key r][q l31], 2 accumulator chains
    const unsigned short* Kb = kbf + (size_t)(nb*32) * DIM;   // 32 rows x 128
    float16 sv, sw;
    #pragma unroll
    for (int r = 0; r < 16; ++r) { sv[r] = 0.f; sw[r] = 0.f; }
    #pragma unroll
    for (int ch = 0; ch < 4; ++ch) {
        short8 kf = *(const short8*)(Kb + (size_t)l31*DIM + ch*16 + q5*8);
        sv = __builtin_amdgcn_mfma_f32_32x32x16_bf16(kf, Qf[ch], sv, 0, 0, 0);
        short8 kg2 = *(const short8*)(Kb + (size_t)l31*DIM + (ch+4)*16 + q5*8);
        sw = __builtin_amdgcn_mfma_f32_32x32x16_bf16(kg2, Qf[ch+4], sw, 0, 0, 0);
    }

    // ---- softmax over 32 keys (no max-sub: |s*scale| small for 32-key blocks)
    float lsum = 0.f;
    unsigned pk[8];
    #pragma unroll
    for (int rp = 0; rp < 8; ++rp) {
        float p0 = __builtin_amdgcn_exp2f((sv[2*rp]   + sw[2*rp])   * kp);
        float p1 = __builtin_amdgcn_exp2f((sv[2*rp+1] + sw[2*rp+1]) * kp);
        lsum += p0 + p1;
        pk[rp] = pack_bf16(p0, p1);
    }
    unsigned e0 = __shfl_xor(q5 ? pk[0] : pk[2], 32, 64);
    unsigned e1 = __shfl_xor(q5 ? pk[1] : pk[3], 32, 64);
    unsigned e2 = __shfl_xor(q5 ? pk[4] : pk[6], 32, 64);
    unsigned e3 = __shfl_xor(q5 ? pk[5] : pk[7], 32, 64);
    FR c0, c1;
    if (q5 == 0) {
        c0.u[0]=pk[0]; c0.u[1]=pk[1]; c0.u[2]=e0;    c0.u[3]=e1;
        c1.u[0]=pk[4]; c1.u[1]=pk[5]; c1.u[2]=e2;    c1.u[3]=e3;
    } else {
        c0.u[0]=e0;    c0.u[1]=e1;    c0.u[2]=pk[2]; c0.u[3]=pk[3];
        c1.u[0]=e2;    c1.u[1]=e3;    c1.u[2]=pk[6]; c1.u[3]=pk[7];
    }
    const float ltot = lsum + __shfl_xor(lsum, 32, 64);

    // ---- PV: V^T frags direct from vtg [h][d][seq]
    const unsigned short* Vb = vtg + (size_t)bh*DIM*SEQ + (size_t)(nb & 63)*32;
    float16 o[4];
    #pragma unroll
    for (int mt = 0; mt < 4; ++mt)
        #pragma unroll
        for (int r = 0; r < 16; ++r) o[mt][r] = 0.f;
    #pragma unroll
    for (int c = 0; c < 2; ++c) {
        short8 pf = c ? c1.s : c0.s;
        #pragma unroll
        for (int mt = 0; mt < 4; ++mt) {
            short8 vf = *(const short8*)(Vb + (size_t)(mt*32 + l31)*SEQ + c*16 + q5*8);
            o[mt] = __builtin_amdgcn_mfma_f32_32x32x16_bf16(vf, pf, o[mt], 0, 0, 0);
        }
    }

    // ---- (oc - oa)^2 accumulation, same reg->d mapping as dense epilogue
    const float inv = 1.f / ltot;
    const float* oa_row = outg + (size_t)(nb*32 + l31) * DIM;
    float sq = 0.f;
    #pragma unroll
    for (int mt = 0; mt < 4; ++mt)
        #pragma unroll
        for (int rg = 0; rg < 4; ++rg) {
            const int d0 = mt*32 + rg*8 + q5*4;
            float4 oa = *(const float4*)(oa_row + d0);
            float dx = o[mt][rg*4+0]*inv - oa.x;
            float dy = o[mt][rg*4+1]*inv - oa.y;
            float dz = o[mt][rg*4+2]*inv - oa.z;
            float dw = o[mt][rg*4+3]*inv - oa.w;
            sq += dx*dx + dy*dy + dz*dz + dw*dw;
        }
    #pragma unroll
    for (int off = 32; off > 0; off >>= 1) sq += __shfl_down(sq, off, 64);
    if (lane == 0) wsum[w] = sq;
    __syncthreads();
    if (t == 0) atomicAdd(lossp, (wsum[0]+wsum[1]+wsum[2]+wsum[3]) * (1.0f/8388608.0f));
}

extern "C" void kernel_launch(void* const* d_in, const int* in_sizes, int n_in,
                              void* d_out, int out_size, void* d_ws, size_t ws_size,
                              hipStream_t stream)
{
    const float* q    = (const float*)d_in[0];
    const float* k    = (const float*)d_in[1];
    const float* v    = (const float*)d_in[2];
    const float* proj = (const float*)d_in[3];
    float* out   = (float*)d_out;
    float* lossp = out + (out_size - 1);

    int* qh   = (int*)d_ws;
    int* kh   = qh + NROWS;
    int* sidx = kh + NROWS;
    int* qhs  = sidx + NROWS;
    unsigned short* kbf = (unsigned short*)(qhs + NROWS);    // 16 MB
    unsigned short* vtg = kbf + (size_t)NROWS*DIM;           // 16 MB

    hipMemsetAsync(lossp, 0, sizeof(float), stream);
    prep_kernel<<<NBH*32, 256, 0, stream>>>(k, v, kbf, vtg);
    hash_kernel<<<(2*NROWS)/16, 256, 0, stream>>>(q, k, proj, qh, kh);
    sort_kernel<<<NBH, 256, 0, stream>>>(qh, sidx, qhs);
    dense_attn_mfma<<<256, 256, 0, stream>>>(kbf, vtg, q, out);
    crit_attn<<<NBLK/4, 256, 0, stream>>>(kbf, vtg, q, sidx, kh, qhs, out, lossp);
}

// Round 5
// 289.851 us; speedup vs baseline: 1.0960x; 1.0960x over previous
//
#include <hip/hip_runtime.h>
#include <hip/hip_bf16.h>

#define SEQ 2048
#define DIM 128
#define NBH 32
#define NROWS (NBH*SEQ)      // 65536
#define NBLK (NROWS/32)      // 2048
#define SCALE 0.08838834764831845f  // 1/sqrt(128)
#define QSC (0.08838834764831845f * 1.4426950408889634f)  // SCALE*log2(e): exp2(s') == exp(s*SCALE)

typedef __attribute__((ext_vector_type(8))) short short8;
typedef __attribute__((ext_vector_type(16))) float float16;

__device__ __forceinline__ unsigned short f2bf(float x) {
    union { float f; unsigned u; } v; v.f = x;
    unsigned r = v.u + 0x7fffu + ((v.u >> 16) & 1u);   // RNE
    return (unsigned short)(r >> 16);
}
__device__ __forceinline__ unsigned pack_bf16(float a, float b) {
    float2 f; f.x = a; f.y = b;
    __hip_bfloat162 h = __float22bfloat162_rn(f);
    union { __hip_bfloat162 h2; unsigned u; } cv; cv.h2 = h; return cv.u;
}
__device__ __forceinline__ void gl_lds16(const void* g, void* l) {
    __builtin_amdgcn_global_load_lds((const __attribute__((address_space(1))) unsigned int*)g,
                                     (__attribute__((address_space(3))) unsigned int*)l, 16, 0, 0);
}

// ---------------- LSH hash: PERM[code] == code ^ (code>>1)
// 4 rows per wave: 16-lane groups, 8 d-elements per lane, proj slice held in regs.
__global__ __launch_bounds__(256) void hash_kernel(const float* __restrict__ qg, const float* __restrict__ kg,
                            const float* __restrict__ proj,
                            int* __restrict__ qh, int* __restrict__ kh)
{
    const int gw   = (int)((blockIdx.x * blockDim.x + threadIdx.x) >> 6);
    const int lane = threadIdx.x & 63;
    const int sub  = lane >> 4;            // row-in-group 0..3
    const int dl   = (lane & 15) * 8;      // d-chunk base
    const int r    = gw * 4 + sub;
    const float* src; int* dst; int row;
    if (r < NROWS) { src = qg; dst = qh; row = r; }
    else           { src = kg; dst = kh; row = r - NROWS; }

    const float* x = src + (size_t)row * DIM + dl;
    float xv[8];
    {
        float4 f0 = *(const float4*)x;
        float4 f1 = *(const float4*)(x + 4);
        xv[0]=f0.x; xv[1]=f0.y; xv[2]=f0.z; xv[3]=f0.w;
        xv[4]=f1.x; xv[5]=f1.y; xv[6]=f1.z; xv[7]=f1.w;
    }
    float pj[56];
    #pragma unroll
    for (int i = 0; i < 14; ++i)
        *(float4*)&pj[i*4] = *(const float4*)(proj + dl*7 + i*4);

    float a[7] = {0.f,0.f,0.f,0.f,0.f,0.f,0.f};
    #pragma unroll
    for (int d = 0; d < 8; ++d)
        #pragma unroll
        for (int p = 0; p < 7; ++p) a[p] = fmaf(xv[d], pj[d*7+p], a[p]);

    #pragma unroll
    for (int off = 1; off < 16; off <<= 1)
        #pragma unroll
        for (int p = 0; p < 7; ++p) a[p] += __shfl_xor(a[p], off, 64);

    if ((lane & 15) == 0) {
        int code = 0;
        if (a[0] > 0.f) code |= 1;  if (a[1] > 0.f) code |= 2;
        if (a[2] > 0.f) code |= 4;  if (a[3] > 0.f) code |= 8;
        if (a[4] > 0.f) code |= 16; if (a[5] > 0.f) code |= 32;
        if (a[6] > 0.f) code |= 64;
        dst[row] = code ^ (code >> 1);
    }
}

// ---------------- parallel stable counting sort per (b,h)
__global__ __launch_bounds__(256) void sort_kernel(const int* __restrict__ qh,
                                                   int* __restrict__ sidx, int* __restrict__ qhs)
{
    __shared__ unsigned short cnt[128][260];
    __shared__ int startv[128];
    const int bh = blockIdx.x;
    const int t  = threadIdx.x;
    const int base = bh*SEQ;

    for (int i = t; i < 128*260; i += 256) ((unsigned short*)cnt)[i] = 0;
    __syncthreads();

    int hv[8];
    {
        int4 a = *(const int4*)(qh + base + t*8);
        int4 b = *(const int4*)(qh + base + t*8 + 4);
        hv[0]=a.x; hv[1]=a.y; hv[2]=a.z; hv[3]=a.w;
        hv[4]=b.x; hv[5]=b.y; hv[6]=b.z; hv[7]=b.w;
    }
    #pragma unroll
    for (int i = 0; i < 8; ++i) cnt[hv[i]][t]++;
    __syncthreads();

    // per-value exclusive column prefix: wave wv handles values wv, wv+4, ...
    const int wv = t >> 6, l = t & 63;
    #pragma unroll 1
    for (int v = wv; v < 128; v += 4) {
        ushort4 cc = *(const ushort4*)&cnt[v][4*l];
        unsigned c0 = cc.x, c1 = cc.y, c2 = cc.z, c3 = cc.w;
        unsigned s01 = c0 + c1;
        unsigned s = s01 + c2 + c3;
        unsigned inc = s;
        #pragma unroll
        for (int off = 1; off < 64; off <<= 1) {
            unsigned o = __shfl_up(inc, off, 64);
            if (l >= off) inc += o;
        }
        unsigned ex = inc - s;
        ushort4 wb;
        wb.x = (unsigned short)ex;
        wb.y = (unsigned short)(ex + c0);
        wb.z = (unsigned short)(ex + s01);
        wb.w = (unsigned short)(ex + s01 + c2);
        *(ushort4*)&cnt[v][4*l] = wb;
        if (l == 63) cnt[v][256] = (unsigned short)inc;   // total count of v
    }
    __syncthreads();

    // exclusive prefix over the 128 per-value totals (wave 0, 2 values/lane)
    if (t < 64) {
        int a0 = cnt[2*t][256], a1 = cnt[2*t+1][256];
        int s2 = a0 + a1, inc = s2;
        #pragma unroll
        for (int off = 1; off < 64; off <<= 1) {
            int o = __shfl_up(inc, off, 64);
            if (t >= off) inc += o;
        }
        int ex = inc - s2;
        startv[2*t]   = ex;
        startv[2*t+1] = ex + a0;
    }
    __syncthreads();

    #pragma unroll
    for (int i = 0; i < 8; ++i) {
        const int v = hv[i];
        int prior = 0;
        #pragma unroll
        for (int j = 0; j < 8; ++j) if (j < i && hv[j] == v) ++prior;
        const int rank = startv[v] + (int)cnt[v][t] + prior;
        sidx[base + rank] = t*8 + i;
        qhs[base + rank]  = v;
    }
}

// ---------------- prep: K -> bf16 row-major; V -> bf16 transposed [h][d][key]
__global__ __launch_bounds__(256) void prep_kernel(const float* __restrict__ kg,
                                                   const float* __restrict__ vg,
                                                   unsigned short* __restrict__ kbf,
                                                   unsigned short* __restrict__ vtg)
{
    __shared__ unsigned short T[128][72];
    const int t  = threadIdx.x;
    const int h  = blockIdx.x >> 5;
    const int sl = blockIdx.x & 31;
    const size_t base = ((size_t)h*SEQ + sl*64) * DIM;

    #pragma unroll
    for (int i = 0; i < 8; ++i) {
        const float4 f = *(const float4*)(kg + base + ((size_t)i*256 + t)*4);
        uint2 pk; pk.x = pack_bf16(f.x, f.y); pk.y = pack_bf16(f.z, f.w);
        *(uint2*)(kbf + base + ((size_t)i*256 + t)*4) = pk;
    }

    const int kk = t & 63, seg = t >> 6;
    #pragma unroll
    for (int i = 0; i < 8; ++i) {
        float4 f = *(const float4*)(vg + base + (size_t)kk*DIM + seg*32 + i*4);
        T[seg*32 + i*4 + 0][kk] = f2bf(f.x);
        T[seg*32 + i*4 + 1][kk] = f2bf(f.y);
        T[seg*32 + i*4 + 2][kk] = f2bf(f.z);
        T[seg*32 + i*4 + 3][kk] = f2bf(f.w);
    }
    __syncthreads();
    const int r = t >> 1, hf = t & 1;
    unsigned short* dst = vtg + ((size_t)h*DIM + r)*SEQ + sl*64 + hf*32;
    #pragma unroll
    for (int i = 0; i < 4; ++i)
        *(short8*)(dst + i*8) = *(const short8*)&T[r][hf*32 + i*8];
}

// ---------------- dense flash attention: bf16 MFMA, double-buffered LDS staging.
// This round: FRAGMENT-ORDERED LDS. Round-4's conflict counter proved conflicts scale
// with ds_reads (~4 extra cy per b128: the (r&7) XOR swizzle only spreads 8 granule
// positions -> 4 lanes per bank class). Fix: store each K/V MFMA fragment in exact
// wave-read order [combo][lane][16B] (gl_lds writes base+lane*16 linearly; the per-lane
// GLOBAL source address selects the fragment element). Body reads become
// &LDS[imm + lane*16] -- 64 lanes over 1024 contiguous bytes = canonical conflict-free
// b128 (m134, 12cy), chunk selection via compile-time offset immediates (koff/voff ALU
// gone). Schedule/geometry = round-0 proven best (32q/wave, 512 blocks, __syncthreads).
__global__ __launch_bounds__(256, 2) void dense_attn_mfma(
    const unsigned short* __restrict__ kbf, const unsigned short* __restrict__ vtg,
    const float* __restrict__ qg, float* __restrict__ outg)
{
    __shared__ __align__(16) unsigned short KbF[2*8192];   // [buf][s*8+ch][lane*8] frag-ordered
    __shared__ __align__(16) unsigned short VbF[2*8192];   // [buf][s*8+c*4+mt][lane*8]

    const int t    = threadIdx.x;
    const int lane = t & 63;
    const int w    = t >> 6;
    const int q5   = lane >> 5;
    const int l31  = lane & 31;
    const int lvec = lane * 8;        // shorts: lane*16B

    const int b    = blockIdx.x;      // 512 blocks
    const int slot = b >> 3;
    const int head = (b & 7) * 4 + (slot >> 4);   // XCD swizzle
    const int qblk = slot & 15;

    const float* Qg = qg + ((size_t)head*SEQ + qblk*128 + w*32) * DIM;
    const unsigned short* Kh = kbf + (size_t)head*SEQ*DIM;
    const unsigned short* Vh = vtg + (size_t)head*DIM*SEQ;

    // ---- staging pointers, fragment-ordered (advance by const per tile)
    // K combo = w*4+i = s*8+ch: lane fetches K[key = s*32+(l&31)][d = ch*16+(l>>5)*8 ..+8]
    // V combo (s=w>>1, c=w&1, mt=i): lane fetches V^T[d = mt*32+(l&31)][key = s*32+c*16+(l>>5)*8 ..+8]
    const unsigned short* kgp[4]; unsigned short* kls[4];
    const unsigned short* vgp[4]; unsigned short* vls[4];
    {
        const int ks = w >> 1, vs = w >> 1, vc = w & 1;   // K: s = (w*4+i)>>3 = w>>1
        #pragma unroll
        for (int i = 0; i < 4; ++i) {
            const int kch = (w & 1) * 4 + i;              // ch = (w*4+i)&7
            kgp[i] = Kh + (size_t)(ks*32 + l31)*DIM + kch*16 + q5*8;   // += 8192/tile
            kls[i] = KbF + (ks*8 + kch)*512;
            vgp[i] = Vh + (size_t)(i*32 + l31)*SEQ + vs*32 + vc*16 + q5*8;  // += 64/tile
            vls[i] = VbF + (vs*8 + vc*4 + i)*512;
        }
    }

    auto stage = [&](const int buf) {
        #pragma unroll
        for (int i = 0; i < 4; ++i) gl_lds16(kgp[i], kls[i] + buf*8192);
        #pragma unroll
        for (int i = 0; i < 4; ++i) gl_lds16(vgp[i], vls[i] + buf*8192);
        #pragma unroll
        for (int i = 0; i < 4; ++i) { kgp[i] += 8192; vgp[i] += 64; }
    };

    stage(0);   // tile 0 DMA overlaps Q-frag load/pack below

    // ---- Q frags (B-operand), pre-scaled by SCALE*log2e
    union FR { unsigned u[4]; short8 s; };
    short8 Qf[8];
    #pragma unroll
    for (int ch = 0; ch < 8; ++ch) {
        const float* p = Qg + (size_t)l31*DIM + ch*16 + q5*8;
        float4 f0 = *(const float4*)p;
        float4 f1 = *(const float4*)(p + 4);
        FR fr;
        fr.u[0] = pack_bf16(f0.x*QSC, f0.y*QSC);
        fr.u[1] = pack_bf16(f0.z*QSC, f0.w*QSC);
        fr.u[2] = pack_bf16(f1.x*QSC, f1.y*QSC);
        fr.u[3] = pack_bf16(f1.z*QSC, f1.w*QSC);
        Qf[ch] = fr.s;
    }

    float16 o[4];
    #pragma unroll
    for (int mt = 0; mt < 4; ++mt)
        #pragma unroll
        for (int r = 0; r < 16; ++r) o[mt][r] = 0.f;
    float lsum = 0.f;

    auto body = [&](const int buf) {
        const int B = buf*8192;
        #pragma unroll
        for (int s = 0; s < 2; ++s) {
            float16 sv;
            #pragma unroll
            for (int r = 0; r < 16; ++r) sv[r] = 0.f;
            #pragma unroll
            for (int ch = 0; ch < 8; ++ch) {
                short8 kf = *(const short8*)&KbF[B + s*4096 + ch*512 + lvec];
                sv = __builtin_amdgcn_mfma_f32_32x32x16_bf16(kf, Qf[ch], sv, 0, 0, 0);
            }
            unsigned pk[8];
            #pragma unroll
            for (int rp = 0; rp < 8; ++rp) {
                float p0 = __builtin_amdgcn_exp2f(sv[2*rp]);
                float p1 = __builtin_amdgcn_exp2f(sv[2*rp+1]);
                lsum += p0 + p1;
                pk[rp] = pack_bf16(p0, p1);
            }
            unsigned e0 = __shfl_xor(q5 ? pk[0] : pk[2], 32, 64);
            unsigned e1 = __shfl_xor(q5 ? pk[1] : pk[3], 32, 64);
            unsigned e2 = __shfl_xor(q5 ? pk[4] : pk[6], 32, 64);
            unsigned e3 = __shfl_xor(q5 ? pk[5] : pk[7], 32, 64);
            FR c0, c1;
            if (q5 == 0) {
                c0.u[0]=pk[0]; c0.u[1]=pk[1]; c0.u[2]=e0;    c0.u[3]=e1;
                c1.u[0]=pk[4]; c1.u[1]=pk[5]; c1.u[2]=e2;    c1.u[3]=e3;
            } else {
                c0.u[0]=e0;    c0.u[1]=e1;    c0.u[2]=pk[2]; c0.u[3]=pk[3];
                c1.u[0]=e2;    c1.u[1]=e3;    c1.u[2]=pk[6]; c1.u[3]=pk[7];
            }
            #pragma unroll
            for (int c = 0; c < 2; ++c) {
                short8 pf = c ? c1.s : c0.s;
                #pragma unroll
                for (int mt = 0; mt < 4; ++mt) {
                    short8 vf = *(const short8*)&VbF[B + s*4096 + c*2048 + mt*512 + lvec];
                    o[mt] = __builtin_amdgcn_mfma_f32_32x32x16_bf16(vf, pf, o[mt], 0, 0, 0);
                }
            }
        }
    };

    #pragma unroll 1
    for (int kt2 = 0; kt2 < 16; ++kt2) {
        __syncthreads();                    // buf0 (tile 2*kt2) ready (DMA drained by barrier)
        stage(1);                           // tile 2*kt2+1 -> buf1
        body(0);                            // consume tile 2*kt2
        __syncthreads();                    // buf1 ready; buf0 reads done
        if (kt2 < 15) stage(0);             // tile 2*kt2+2 -> buf0
        body(1);                            // consume tile 2*kt2+1
    }

    const float l = lsum + __shfl_xor(lsum, 32, 64);
    const float inv = 1.f / l;
    float* orow = outg + ((size_t)head*SEQ + qblk*128 + w*32 + l31) * DIM;
    #pragma unroll
    for (int mt = 0; mt < 4; ++mt)
        #pragma unroll
        for (int rg = 0; rg < 4; ++rg) {
            const int d0 = mt*32 + rg*8 + q5*4;
            float4 ov;
            ov.x = o[mt][rg*4+0]*inv; ov.y = o[mt][rg*4+1]*inv;
            ov.z = o[mt][rg*4+2]*inv; ov.w = o[mt][rg*4+3]*inv;
            *(float4*)(orow + d0) = ov;
        }
}

// ---------------- blocked critical attention + MSE loss: one wave per 32-block,
// bf16 MFMA, fp32 accum, ZERO LDS. criticality fused in via ballot on kh==qhs.
__global__ __launch_bounds__(256) void crit_attn(
    const unsigned short* __restrict__ kbf, const unsigned short* __restrict__ vtg,
    const float* __restrict__ qg, const int* __restrict__ sidx,
    const int* __restrict__ kh, const int* __restrict__ qhs,
    const float* __restrict__ outg, float* __restrict__ lossp)
{
    __shared__ float wsum[4];
    const int t    = threadIdx.x;
    const int lane = t & 63;
    const int w    = t >> 6;
    const int nb   = blockIdx.x * 4 + w;          // 0..2047
    const int q5   = lane >> 5;
    const int l31  = lane & 31;
    const int bh   = nb >> 6;

    // ---- fused criticality: keep = 1 iff zero hash matches in this 32-block
    const int khv = kh[nb*32 + l31];
    const int qhv = qhs[nb*32 + l31];
    const unsigned long long mm = __ballot(khv == qhv);
    const float kp = ((mm & 0xffffffffull) == 0ull) ? 1.0f : 0.0f;

    const int qrow = sidx[bh*SEQ + (nb & 63)*32 + l31];

    // ---- Q frags (B-operand), gathered rows, pre-scaled by SCALE*log2e
    union FR { unsigned u[4]; short8 s; };
    short8 Qf[8];
    const float* Qg = qg + ((size_t)bh*SEQ + qrow) * DIM;
    #pragma unroll
    for (int ch = 0; ch < 8; ++ch) {
        const float* p = Qg + ch*16 + q5*8;
        float4 f0 = *(const float4*)p;
        float4 f1 = *(const float4*)(p + 4);
        FR fr;
        fr.u[0] = pack_bf16(f0.x*QSC, f0.y*QSC);
        fr.u[1] = pack_bf16(f0.z*QSC, f0.w*QSC);
        fr.u[2] = pack_bf16(f1.x*QSC, f1.y*QSC);
        fr.u[3] = pack_bf16(f1.z*QSC, f1.w*QSC);
        Qf[ch] = fr.s;
    }

    // ---- QK^T: S[key r][q l31], 2 accumulator chains
    const unsigned short* Kb = kbf + (size_t)(nb*32) * DIM;   // 32 rows x 128
    float16 sv, sw;
    #pragma unroll
    for (int r = 0; r < 16; ++r) { sv[r] = 0.f; sw[r] = 0.f; }
    #pragma unroll
    for (int ch = 0; ch < 4; ++ch) {
        short8 kf = *(const short8*)(Kb + (size_t)l31*DIM + ch*16 + q5*8);
        sv = __builtin_amdgcn_mfma_f32_32x32x16_bf16(kf, Qf[ch], sv, 0, 0, 0);
        short8 kg2 = *(const short8*)(Kb + (size_t)l31*DIM + (ch+4)*16 + q5*8);
        sw = __builtin_amdgcn_mfma_f32_32x32x16_bf16(kg2, Qf[ch+4], sw, 0, 0, 0);
    }

    // ---- softmax over 32 keys (no max-sub: |s*scale| small for 32-key blocks)
    float lsum = 0.f;
    unsigned pk[8];
    #pragma unroll
    for (int rp = 0; rp < 8; ++rp) {
        float p0 = __builtin_amdgcn_exp2f((sv[2*rp]   + sw[2*rp])   * kp);
        float p1 = __builtin_amdgcn_exp2f((sv[2*rp+1] + sw[2*rp+1]) * kp);
        lsum += p0 + p1;
        pk[rp] = pack_bf16(p0, p1);
    }
    unsigned e0 = __shfl_xor(q5 ? pk[0] : pk[2], 32, 64);
    unsigned e1 = __shfl_xor(q5 ? pk[1] : pk[3], 32, 64);
    unsigned e2 = __shfl_xor(q5 ? pk[4] : pk[6], 32, 64);
    unsigned e3 = __shfl_xor(q5 ? pk[5] : pk[7], 32, 64);
    FR c0, c1;
    if (q5 == 0) {
        c0.u[0]=pk[0]; c0.u[1]=pk[1]; c0.u[2]=e0;    c0.u[3]=e1;
        c1.u[0]=pk[4]; c1.u[1]=pk[5]; c1.u[2]=e2;    c1.u[3]=e3;
    } else {
        c0.u[0]=e0;    c0.u[1]=e1;    c0.u[2]=pk[2]; c0.u[3]=pk[3];
        c1.u[0]=e2;    c1.u[1]=e3;    c1.u[2]=pk[6]; c1.u[3]=pk[7];
    }
    const float ltot = lsum + __shfl_xor(lsum, 32, 64);

    // ---- PV: V^T frags direct from vtg [h][d][seq]
    const unsigned short* Vb = vtg + (size_t)bh*DIM*SEQ + (size_t)(nb & 63)*32;
    float16 o[4];
    #pragma unroll
    for (int mt = 0; mt < 4; ++mt)
        #pragma unroll
        for (int r = 0; r < 16; ++r) o[mt][r] = 0.f;
    #pragma unroll
    for (int c = 0; c < 2; ++c) {
        short8 pf = c ? c1.s : c0.s;
        #pragma unroll
        for (int mt = 0; mt < 4; ++mt) {
            short8 vf = *(const short8*)(Vb + (size_t)(mt*32 + l31)*SEQ + c*16 + q5*8);
            o[mt] = __builtin_amdgcn_mfma_f32_32x32x16_bf16(vf, pf, o[mt], 0, 0, 0);
        }
    }

    // ---- (oc - oa)^2 accumulation, same reg->d mapping as dense epilogue
    const float inv = 1.f / ltot;
    const float* oa_row = outg + (size_t)(nb*32 + l31) * DIM;
    float sq = 0.f;
    #pragma unroll
    for (int mt = 0; mt < 4; ++mt)
        #pragma unroll
        for (int rg = 0; rg < 4; ++rg) {
            const int d0 = mt*32 + rg*8 + q5*4;
            float4 oa = *(const float4*)(oa_row + d0);
            float dx = o[mt][rg*4+0]*inv - oa.x;
            float dy = o[mt][rg*4+1]*inv - oa.y;
            float dz = o[mt][rg*4+2]*inv - oa.z;
            float dw = o[mt][rg*4+3]*inv - oa.w;
            sq += dx*dx + dy*dy + dz*dz + dw*dw;
        }
    #pragma unroll
    for (int off = 32; off > 0; off >>= 1) sq += __shfl_down(sq, off, 64);
    if (lane == 0) wsum[w] = sq;
    __syncthreads();
    if (t == 0) atomicAdd(lossp, (wsum[0]+wsum[1]+wsum[2]+wsum[3]) * (1.0f/8388608.0f));
}

extern "C" void kernel_launch(void* const* d_in, const int* in_sizes, int n_in,
                              void* d_out, int out_size, void* d_ws, size_t ws_size,
                              hipStream_t stream)
{
    const float* q    = (const float*)d_in[0];
    const float* k    = (const float*)d_in[1];
    const float* v    = (const float*)d_in[2];
    const float* proj = (const float*)d_in[3];
    float* out   = (float*)d_out;
    float* lossp = out + (out_size - 1);

    int* qh   = (int*)d_ws;
    int* kh   = qh + NROWS;
    int* sidx = kh + NROWS;
    int* qhs  = sidx + NROWS;
    unsigned short* kbf = (unsigned short*)(qhs + NROWS);    // 16 MB
    unsigned short* vtg = kbf + (size_t)NROWS*DIM;           // 16 MB

    hipMemsetAsync(lossp, 0, sizeof(float), stream);
    prep_kernel<<<NBH*32, 256, 0, stream>>>(k, v, kbf, vtg);
    hash_kernel<<<(2*NROWS)/16, 256, 0, stream>>>(q, k, proj, qh, kh);
    sort_kernel<<<NBH, 256, 0, stream>>>(qh, sidx, qhs);
    dense_attn_mfma<<<512, 256, 0, stream>>>(kbf, vtg, q, out);
    crit_attn<<<NBLK/4, 256, 0, stream>>>(kbf, vtg, q, sidx, kh, qhs, out, lossp);
}

// Round 6
// 278.844 us; speedup vs baseline: 1.1393x; 1.0395x over previous
//
#include <hip/hip_runtime.h>
#include <hip/hip_bf16.h>

#define SEQ 2048
#define DIM 128
#define NBH 32
#define NROWS (NBH*SEQ)      // 65536
#define NBLK (NROWS/32)      // 2048
#define SCALE 0.08838834764831845f  // 1/sqrt(128)
#define QSC (0.08838834764831845f * 1.4426950408889634f)  // SCALE*log2(e): exp2(s') == exp(s*SCALE)

typedef __attribute__((ext_vector_type(8))) short short8;
typedef __attribute__((ext_vector_type(16))) float float16;

__device__ __forceinline__ unsigned short f2bf(float x) {
    union { float f; unsigned u; } v; v.f = x;
    unsigned r = v.u + 0x7fffu + ((v.u >> 16) & 1u);   // RNE
    return (unsigned short)(r >> 16);
}
__device__ __forceinline__ unsigned pack_bf16(float a, float b) {
    float2 f; f.x = a; f.y = b;
    __hip_bfloat162 h = __float22bfloat162_rn(f);
    union { __hip_bfloat162 h2; unsigned u; } cv; cv.h2 = h; return cv.u;
}
__device__ __forceinline__ void gl_lds16(const void* g, void* l) {
    __builtin_amdgcn_global_load_lds((const __attribute__((address_space(1))) unsigned int*)g,
                                     (__attribute__((address_space(3))) unsigned int*)l, 16, 0, 0);
}

// ---------------- LSH hash: PERM[code] == code ^ (code>>1)
// 4 rows per wave: 16-lane groups, 8 d-elements per lane, proj slice held in regs.
__global__ __launch_bounds__(256) void hash_kernel(const float* __restrict__ qg, const float* __restrict__ kg,
                            const float* __restrict__ proj,
                            int* __restrict__ qh, int* __restrict__ kh)
{
    const int gw   = (int)((blockIdx.x * blockDim.x + threadIdx.x) >> 6);
    const int lane = threadIdx.x & 63;
    const int sub  = lane >> 4;            // row-in-group 0..3
    const int dl   = (lane & 15) * 8;      // d-chunk base
    const int r    = gw * 4 + sub;
    const float* src; int* dst; int row;
    if (r < NROWS) { src = qg; dst = qh; row = r; }
    else           { src = kg; dst = kh; row = r - NROWS; }

    const float* x = src + (size_t)row * DIM + dl;
    float xv[8];
    {
        float4 f0 = *(const float4*)x;
        float4 f1 = *(const float4*)(x + 4);
        xv[0]=f0.x; xv[1]=f0.y; xv[2]=f0.z; xv[3]=f0.w;
        xv[4]=f1.x; xv[5]=f1.y; xv[6]=f1.z; xv[7]=f1.w;
    }
    float pj[56];
    #pragma unroll
    for (int i = 0; i < 14; ++i)
        *(float4*)&pj[i*4] = *(const float4*)(proj + dl*7 + i*4);

    float a[7] = {0.f,0.f,0.f,0.f,0.f,0.f,0.f};
    #pragma unroll
    for (int d = 0; d < 8; ++d)
        #pragma unroll
        for (int p = 0; p < 7; ++p) a[p] = fmaf(xv[d], pj[d*7+p], a[p]);

    #pragma unroll
    for (int off = 1; off < 16; off <<= 1)
        #pragma unroll
        for (int p = 0; p < 7; ++p) a[p] += __shfl_xor(a[p], off, 64);

    if ((lane & 15) == 0) {
        int code = 0;
        if (a[0] > 0.f) code |= 1;  if (a[1] > 0.f) code |= 2;
        if (a[2] > 0.f) code |= 4;  if (a[3] > 0.f) code |= 8;
        if (a[4] > 0.f) code |= 16; if (a[5] > 0.f) code |= 32;
        if (a[6] > 0.f) code |= 64;
        dst[row] = code ^ (code >> 1);
    }
}

// ---------------- parallel stable counting sort per (b,h)
__global__ __launch_bounds__(256) void sort_kernel(const int* __restrict__ qh,
                                                   int* __restrict__ sidx, int* __restrict__ qhs)
{
    __shared__ __align__(16) unsigned short cnt[128][260];
    __shared__ int startv[128];
    const int bh = blockIdx.x;
    const int t  = threadIdx.x;
    const int base = bh*SEQ;

    // vectorized zeroing: 128*260 = 33280 shorts = 4160 short8s
    {
        const short8 z8 = {0,0,0,0,0,0,0,0};
        for (int i = t; i < 4160; i += 256) ((short8*)cnt)[i] = z8;
    }
    __syncthreads();

    int hv[8];
    {
        int4 a = *(const int4*)(qh + base + t*8);
        int4 b = *(const int4*)(qh + base + t*8 + 4);
        hv[0]=a.x; hv[1]=a.y; hv[2]=a.z; hv[3]=a.w;
        hv[4]=b.x; hv[5]=b.y; hv[6]=b.z; hv[7]=b.w;
    }
    #pragma unroll
    for (int i = 0; i < 8; ++i) cnt[hv[i]][t]++;
    __syncthreads();

    // per-value exclusive column prefix: wave wv handles values wv, wv+4, ...
    const int wv = t >> 6, l = t & 63;
    #pragma unroll 1
    for (int v = wv; v < 128; v += 4) {
        ushort4 cc = *(const ushort4*)&cnt[v][4*l];
        unsigned c0 = cc.x, c1 = cc.y, c2 = cc.z, c3 = cc.w;
        unsigned s01 = c0 + c1;
        unsigned s = s01 + c2 + c3;
        unsigned inc = s;
        #pragma unroll
        for (int off = 1; off < 64; off <<= 1) {
            unsigned o = __shfl_up(inc, off, 64);
            if (l >= off) inc += o;
        }
        unsigned ex = inc - s;
        ushort4 wb;
        wb.x = (unsigned short)ex;
        wb.y = (unsigned short)(ex + c0);
        wb.z = (unsigned short)(ex + s01);
        wb.w = (unsigned short)(ex + s01 + c2);
        *(ushort4*)&cnt[v][4*l] = wb;
        if (l == 63) cnt[v][256] = (unsigned short)inc;   // total count of v
    }
    __syncthreads();

    // exclusive prefix over the 128 per-value totals (wave 0, 2 values/lane)
    if (t < 64) {
        int a0 = cnt[2*t][256], a1 = cnt[2*t+1][256];
        int s2 = a0 + a1, inc = s2;
        #pragma unroll
        for (int off = 1; off < 64; off <<= 1) {
            int o = __shfl_up(inc, off, 64);
            if (t >= off) inc += o;
        }
        int ex = inc - s2;
        startv[2*t]   = ex;
        startv[2*t+1] = ex + a0;
    }
    __syncthreads();

    #pragma unroll
    for (int i = 0; i < 8; ++i) {
        const int v = hv[i];
        int prior = 0;
        #pragma unroll
        for (int j = 0; j < 8; ++j) if (j < i && hv[j] == v) ++prior;
        const int rank = startv[v] + (int)cnt[v][t] + prior;
        sidx[base + rank] = t*8 + i;
        qhs[base + rank]  = v;
    }
}

// ---------------- prep: K -> bf16 row-major; V -> bf16 transposed [h][d][key]
__global__ __launch_bounds__(256) void prep_kernel(const float* __restrict__ kg,
                                                   const float* __restrict__ vg,
                                                   unsigned short* __restrict__ kbf,
                                                   unsigned short* __restrict__ vtg)
{
    __shared__ unsigned short T[128][72];
    const int t  = threadIdx.x;
    const int h  = blockIdx.x >> 5;
    const int sl = blockIdx.x & 31;
    const size_t base = ((size_t)h*SEQ + sl*64) * DIM;

    #pragma unroll
    for (int i = 0; i < 8; ++i) {
        const float4 f = *(const float4*)(kg + base + ((size_t)i*256 + t)*4);
        uint2 pk; pk.x = pack_bf16(f.x, f.y); pk.y = pack_bf16(f.z, f.w);
        *(uint2*)(kbf + base + ((size_t)i*256 + t)*4) = pk;
    }

    const int kk = t & 63, seg = t >> 6;
    #pragma unroll
    for (int i = 0; i < 8; ++i) {
        float4 f = *(const float4*)(vg + base + (size_t)kk*DIM + seg*32 + i*4);
        T[seg*32 + i*4 + 0][kk] = f2bf(f.x);
        T[seg*32 + i*4 + 1][kk] = f2bf(f.y);
        T[seg*32 + i*4 + 2][kk] = f2bf(f.z);
        T[seg*32 + i*4 + 3][kk] = f2bf(f.w);
    }
    __syncthreads();
    const int r = t >> 1, hf = t & 1;
    unsigned short* dst = vtg + ((size_t)h*DIM + r)*SEQ + sl*64 + hf*32;
    #pragma unroll
    for (int i = 0; i < 4; ++i)
        *(short8*)(dst + i*8) = *(const short8*)&T[r][hf*32 + i*8];
}

// ---------------- dense flash attention: ROUND-0 STRUCTURE RESTORED (proven 89.8 us:
// koff/voff XOR layout, plain __syncthreads double-buffer, 512 blocks = 2 blocks/CU).
// Five schedule/layout variants all regressed (counted-vmcnt 91.9, fused-barrier 96.5,
// 64q/wave 127.5-spills, zero-conflict gather-staging 103). ONE addition vs round-0:
// s_setprio(1) around MFMA clusters (T5; m191 prior: +4-7% for independently-phased
// attn blocks; never isolated on this structure before).
__global__ __launch_bounds__(256, 2) void dense_attn_mfma(
    const unsigned short* __restrict__ kbf, const unsigned short* __restrict__ vtg,
    const float* __restrict__ qg, float* __restrict__ outg)
{
    __shared__ __align__(16) unsigned short KbF[2*8192];   // [buf][key(64) x d(128)]
    __shared__ __align__(16) unsigned short VbF[2*8192];   // [buf][d(128) x key(64)]

    const int t    = threadIdx.x;
    const int lane = t & 63;
    const int w    = t >> 6;
    const int q5   = lane >> 5;
    const int l31  = lane & 31;
    const int e    = l31 & 7;

    const int b    = blockIdx.x;      // 512 blocks
    const int slot = b >> 3;
    const int head = (b & 7) * 4 + (slot >> 4);   // XCD swizzle
    const int qblk = slot & 15;

    const float* Qg = qg + ((size_t)head*SEQ + qblk*128 + w*32) * DIM;
    const unsigned short* Kh = kbf + (size_t)head*SEQ*DIM;
    const unsigned short* Vh = vtg + (size_t)head*DIM*SEQ;

    // ---- kt-invariant LDS read offsets (shorts), swizzle baked in
    int koff[8], voff[4];
    #pragma unroll
    for (int ch = 0; ch < 8; ++ch) koff[ch] = l31*128 + (((2*ch + q5) ^ e) * 8);
    #pragma unroll
    for (int u = 0; u < 4; ++u)    voff[u]  = l31*64  + ((((u>>1)*4 + (u&1)*2 + q5) ^ e) * 8);

    // ---- kt-invariant staging pointers (advance by const per tile)
    const unsigned short* kgp[4]; unsigned short* kls[4];
    const unsigned short* vgp[4]; unsigned short* vls[4];
    #pragma unroll
    for (int i = 0; i < 4; ++i) {
        const int j = w*4 + i;
        const int r = j*4 + (lane >> 4);
        const int u = (lane & 15) ^ (r & 7);
        kgp[i] = Kh + r*DIM + u*8;            // += 8192 per tile
        kls[i] = KbF + j*512;
        const int d = j*8 + (lane >> 3);
        const int u2 = (lane & 7) ^ (d & 7);
        vgp[i] = Vh + (size_t)d*SEQ + u2*8;   // += 64 per tile
        vls[i] = VbF + j*512;
    }

    // ---- Q frags (B-operand), pre-scaled by SCALE*log2e
    union FR { unsigned u[4]; short8 s; };
    short8 Qf[8];
    #pragma unroll
    for (int ch = 0; ch < 8; ++ch) {
        const float* p = Qg + (size_t)l31*DIM + ch*16 + q5*8;
        float4 f0 = *(const float4*)p;
        float4 f1 = *(const float4*)(p + 4);
        FR fr;
        fr.u[0] = pack_bf16(f0.x*QSC, f0.y*QSC);
        fr.u[1] = pack_bf16(f0.z*QSC, f0.w*QSC);
        fr.u[2] = pack_bf16(f1.x*QSC, f1.y*QSC);
        fr.u[3] = pack_bf16(f1.z*QSC, f1.w*QSC);
        Qf[ch] = fr.s;
    }

    float16 o[4];
    #pragma unroll
    for (int mt = 0; mt < 4; ++mt)
        #pragma unroll
        for (int r = 0; r < 16; ++r) o[mt][r] = 0.f;
    float lsum = 0.f;

    auto stage = [&](const int buf) {
        #pragma unroll
        for (int i = 0; i < 4; ++i) gl_lds16(kgp[i], kls[i] + buf*8192);
        #pragma unroll
        for (int i = 0; i < 4; ++i) gl_lds16(vgp[i], vls[i] + buf*8192);
        #pragma unroll
        for (int i = 0; i < 4; ++i) { kgp[i] += 8192; vgp[i] += 64; }
    };

    auto body = [&](const int buf) {
        #pragma unroll
        for (int s = 0; s < 2; ++s) {
            float16 sv;
            #pragma unroll
            for (int r = 0; r < 16; ++r) sv[r] = 0.f;
            __builtin_amdgcn_s_setprio(1);
            #pragma unroll
            for (int ch = 0; ch < 8; ++ch) {
                short8 kf = *(const short8*)&KbF[buf*8192 + s*4096 + koff[ch]];
                sv = __builtin_amdgcn_mfma_f32_32x32x16_bf16(kf, Qf[ch], sv, 0, 0, 0);
            }
            __builtin_amdgcn_s_setprio(0);
            unsigned pk[8];
            #pragma unroll
            for (int rp = 0; rp < 8; ++rp) {
                float p0 = __builtin_amdgcn_exp2f(sv[2*rp]);
                float p1 = __builtin_amdgcn_exp2f(sv[2*rp+1]);
                lsum += p0 + p1;
                pk[rp] = pack_bf16(p0, p1);
            }
            unsigned e0 = __shfl_xor(q5 ? pk[0] : pk[2], 32, 64);
            unsigned e1 = __shfl_xor(q5 ? pk[1] : pk[3], 32, 64);
            unsigned e2 = __shfl_xor(q5 ? pk[4] : pk[6], 32, 64);
            unsigned e3 = __shfl_xor(q5 ? pk[5] : pk[7], 32, 64);
            FR c0, c1;
            if (q5 == 0) {
                c0.u[0]=pk[0]; c0.u[1]=pk[1]; c0.u[2]=e0;    c0.u[3]=e1;
                c1.u[0]=pk[4]; c1.u[1]=pk[5]; c1.u[2]=e2;    c1.u[3]=e3;
            } else {
                c0.u[0]=e0;    c0.u[1]=e1;    c0.u[2]=pk[2]; c0.u[3]=pk[3];
                c1.u[0]=e2;    c1.u[1]=e3;    c1.u[2]=pk[6]; c1.u[3]=pk[7];
            }
            __builtin_amdgcn_s_setprio(1);
            #pragma unroll
            for (int c = 0; c < 2; ++c) {
                short8 pf = c ? c1.s : c0.s;
                #pragma unroll
                for (int mt = 0; mt < 4; ++mt) {
                    short8 vf = *(const short8*)&VbF[buf*8192 + mt*2048 + voff[s*2 + c]];
                    o[mt] = __builtin_amdgcn_mfma_f32_32x32x16_bf16(vf, pf, o[mt], 0, 0, 0);
                }
            }
            __builtin_amdgcn_s_setprio(0);
        }
    };

    stage(0);                               // tile 0 -> buf0
    #pragma unroll 1
    for (int kt2 = 0; kt2 < 16; ++kt2) {
        __syncthreads();                    // buf0 ready (DMA drained by barrier)
        stage(1);                           // tile 2*kt2+1 -> buf1
        body(0);                            // consume tile 2*kt2
        __syncthreads();                    // buf1 ready; buf0 reads done
        if (kt2 < 15) stage(0);             // tile 2*kt2+2 -> buf0
        body(1);                            // consume tile 2*kt2+1
    }

    const float l = lsum + __shfl_xor(lsum, 32, 64);
    const float inv = 1.f / l;
    float* orow = outg + ((size_t)head*SEQ + qblk*128 + w*32 + l31) * DIM;
    #pragma unroll
    for (int mt = 0; mt < 4; ++mt)
        #pragma unroll
        for (int rg = 0; rg < 4; ++rg) {
            const int d0 = mt*32 + rg*8 + q5*4;
            float4 ov;
            ov.x = o[mt][rg*4+0]*inv; ov.y = o[mt][rg*4+1]*inv;
            ov.z = o[mt][rg*4+2]*inv; ov.w = o[mt][rg*4+3]*inv;
            *(float4*)(orow + d0) = ov;
        }
}

// ---------------- blocked critical attention + MSE loss: one wave per 32-block,
// bf16 MFMA, fp32 accum, ZERO LDS. criticality fused in via ballot on kh==qhs.
__global__ __launch_bounds__(256) void crit_attn(
    const unsigned short* __restrict__ kbf, const unsigned short* __restrict__ vtg,
    const float* __restrict__ qg, const int* __restrict__ sidx,
    const int* __restrict__ kh, const int* __restrict__ qhs,
    const float* __restrict__ outg, float* __restrict__ lossp)
{
    __shared__ float wsum[4];
    const int t    = threadIdx.x;
    const int lane = t & 63;
    const int w    = t >> 6;
    const int nb   = blockIdx.x * 4 + w;          // 0..2047
    const int q5   = lane >> 5;
    const int l31  = lane & 31;
    const int bh   = nb >> 6;

    // ---- fused criticality: keep = 1 iff zero hash matches in this 32-block
    const int khv = kh[nb*32 + l31];
    const int qhv = qhs[nb*32 + l31];
    const unsigned long long mm = __ballot(khv == qhv);
    const float kp = ((mm & 0xffffffffull) == 0ull) ? 1.0f : 0.0f;

    const int qrow = sidx[bh*SEQ + (nb & 63)*32 + l31];

    // ---- Q frags (B-operand), gathered rows, pre-scaled by SCALE*log2e
    union FR { unsigned u[4]; short8 s; };
    short8 Qf[8];
    const float* Qg = qg + ((size_t)bh*SEQ + qrow) * DIM;
    #pragma unroll
    for (int ch = 0; ch < 8; ++ch) {
        const float* p = Qg + ch*16 + q5*8;
        float4 f0 = *(const float4*)p;
        float4 f1 = *(const float4*)(p + 4);
        FR fr;
        fr.u[0] = pack_bf16(f0.x*QSC, f0.y*QSC);
        fr.u[1] = pack_bf16(f0.z*QSC, f0.w*QSC);
        fr.u[2] = pack_bf16(f1.x*QSC, f1.y*QSC);
        fr.u[3] = pack_bf16(f1.z*QSC, f1.w*QSC);
        Qf[ch] = fr.s;
    }

    // ---- QK^T: S[key r][q l31], 2 accumulator chains
    const unsigned short* Kb = kbf + (size_t)(nb*32) * DIM;   // 32 rows x 128
    float16 sv, sw;
    #pragma unroll
    for (int r = 0; r < 16; ++r) { sv[r] = 0.f; sw[r] = 0.f; }
    #pragma unroll
    for (int ch = 0; ch < 4; ++ch) {
        short8 kf = *(const short8*)(Kb + (size_t)l31*DIM + ch*16 + q5*8);
        sv = __builtin_amdgcn_mfma_f32_32x32x16_bf16(kf, Qf[ch], sv, 0, 0, 0);
        short8 kg2 = *(const short8*)(Kb + (size_t)l31*DIM + (ch+4)*16 + q5*8);
        sw = __builtin_amdgcn_mfma_f32_32x32x16_bf16(kg2, Qf[ch+4], sw, 0, 0, 0);
    }

    // ---- softmax over 32 keys (no max-sub: |s*scale| small for 32-key blocks)
    float lsum = 0.f;
    unsigned pk[8];
    #pragma unroll
    for (int rp = 0; rp < 8; ++rp) {
        float p0 = __builtin_amdgcn_exp2f((sv[2*rp]   + sw[2*rp])   * kp);
        float p1 = __builtin_amdgcn_exp2f((sv[2*rp+1] + sw[2*rp+1]) * kp);
        lsum += p0 + p1;
        pk[rp] = pack_bf16(p0, p1);
    }
    unsigned e0 = __shfl_xor(q5 ? pk[0] : pk[2], 32, 64);
    unsigned e1 = __shfl_xor(q5 ? pk[1] : pk[3], 32, 64);
    unsigned e2 = __shfl_xor(q5 ? pk[4] : pk[6], 32, 64);
    unsigned e3 = __shfl_xor(q5 ? pk[5] : pk[7], 32, 64);
    FR c0, c1;
    if (q5 == 0) {
        c0.u[0]=pk[0]; c0.u[1]=pk[1]; c0.u[2]=e0;    c0.u[3]=e1;
        c1.u[0]=pk[4]; c1.u[1]=pk[5]; c1.u[2]=e2;    c1.u[3]=e3;
    } else {
        c0.u[0]=e0;    c0.u[1]=e1;    c0.u[2]=pk[2]; c0.u[3]=pk[3];
        c1.u[0]=e2;    c1.u[1]=e3;    c1.u[2]=pk[6]; c1.u[3]=pk[7];
    }
    const float ltot = lsum + __shfl_xor(lsum, 32, 64);

    // ---- PV: V^T frags direct from vtg [h][d][seq]
    const unsigned short* Vb = vtg + (size_t)bh*DIM*SEQ + (size_t)(nb & 63)*32;
    float16 o[4];
    #pragma unroll
    for (int mt = 0; mt < 4; ++mt)
        #pragma unroll
        for (int r = 0; r < 16; ++r) o[mt][r] = 0.f;
    #pragma unroll
    for (int c = 0; c < 2; ++c) {
        short8 pf = c ? c1.s : c0.s;
        #pragma unroll
        for (int mt = 0; mt < 4; ++mt) {
            short8 vf = *(const short8*)(Vb + (size_t)(mt*32 + l31)*SEQ + c*16 + q5*8);
            o[mt] = __builtin_amdgcn_mfma_f32_32x32x16_bf16(vf, pf, o[mt], 0, 0, 0);
        }
    }

    // ---- (oc - oa)^2 accumulation, same reg->d mapping as dense epilogue
    const float inv = 1.f / ltot;
    const float* oa_row = outg + (size_t)(nb*32 + l31) * DIM;
    float sq = 0.f;
    #pragma unroll
    for (int mt = 0; mt < 4; ++mt)
        #pragma unroll
        for (int rg = 0; rg < 4; ++rg) {
            const int d0 = mt*32 + rg*8 + q5*4;
            float4 oa = *(const float4*)(oa_row + d0);
            float dx = o[mt][rg*4+0]*inv - oa.x;
            float dy = o[mt][rg*4+1]*inv - oa.y;
            float dz = o[mt][rg*4+2]*inv - oa.z;
            float dw = o[mt][rg*4+3]*inv - oa.w;
            sq += dx*dx + dy*dy + dz*dz + dw*dw;
        }
    #pragma unroll
    for (int off = 32; off > 0; off >>= 1) sq += __shfl_down(sq, off, 64);
    if (lane == 0) wsum[w] = sq;
    __syncthreads();
    if (t == 0) atomicAdd(lossp, (wsum[0]+wsum[1]+wsum[2]+wsum[3]) * (1.0f/8388608.0f));
}

extern "C" void kernel_launch(void* const* d_in, const int* in_sizes, int n_in,
                              void* d_out, int out_size, void* d_ws, size_t ws_size,
                              hipStream_t stream)
{
    const float* q    = (const float*)d_in[0];
    const float* k    = (const float*)d_in[1];
    const float* v    = (const float*)d_in[2];
    const float* proj = (const float*)d_in[3];
    float* out   = (float*)d_out;
    float* lossp = out + (out_size - 1);

    int* qh   = (int*)d_ws;
    int* kh   = qh + NROWS;
    int* sidx = kh + NROWS;
    int* qhs  = sidx + NROWS;
    unsigned short* kbf = (unsigned short*)(qhs + NROWS);    // 16 MB
    unsigned short* vtg = kbf + (size_t)NROWS*DIM;           // 16 MB

    hipMemsetAsync(lossp, 0, sizeof(float), stream);
    prep_kernel<<<NBH*32, 256, 0, stream>>>(k, v, kbf, vtg);
    hash_kernel<<<(2*NROWS)/16, 256, 0, stream>>>(q, k, proj, qh, kh);
    sort_kernel<<<NBH, 256, 0, stream>>>(qh, sidx, qhs);
    dense_attn_mfma<<<512, 256, 0, stream>>>(kbf, vtg, q, out);
    crit_attn<<<NBLK/4, 256, 0, stream>>>(kbf, vtg, q, sidx, kh, qhs, out, lossp);
}

// Round 7
// 263.299 us; speedup vs baseline: 1.2065x; 1.0590x over previous
//
#include <hip/hip_runtime.h>
#include <hip/hip_bf16.h>

#define SEQ 2048
#define DIM 128
#define NBH 32
#define NROWS (NBH*SEQ)      // 65536
#define NBLK (NROWS/32)      // 2048
#define SCALE 0.08838834764831845f  // 1/sqrt(128)
#define QSC (0.08838834764831845f * 1.4426950408889634f)  // SCALE*log2(e): exp2(s') == exp(s*SCALE)

typedef __attribute__((ext_vector_type(8))) short short8;
typedef __attribute__((ext_vector_type(16))) float float16;

__device__ __forceinline__ unsigned short f2bf(float x) {
    union { float f; unsigned u; } v; v.f = x;
    unsigned r = v.u + 0x7fffu + ((v.u >> 16) & 1u);   // RNE
    return (unsigned short)(r >> 16);
}
__device__ __forceinline__ unsigned pack_bf16(float a, float b) {
    float2 f; f.x = a; f.y = b;
    __hip_bfloat162 h = __float22bfloat162_rn(f);
    union { __hip_bfloat162 h2; unsigned u; } cv; cv.h2 = h; return cv.u;
}
__device__ __forceinline__ void gl_lds16(const void* g, void* l) {
    __builtin_amdgcn_global_load_lds((const __attribute__((address_space(1))) unsigned int*)g,
                                     (__attribute__((address_space(3))) unsigned int*)l, 16, 0, 0);
}

// ---------------- LSH hash: PERM[code] == code ^ (code>>1)
// 4 rows per wave: 16-lane groups, 8 d-elements per lane, proj slice held in regs.
__global__ __launch_bounds__(256) void hash_kernel(const float* __restrict__ qg, const float* __restrict__ kg,
                            const float* __restrict__ proj,
                            int* __restrict__ qh, int* __restrict__ kh)
{
    const int gw   = (int)((blockIdx.x * blockDim.x + threadIdx.x) >> 6);
    const int lane = threadIdx.x & 63;
    const int sub  = lane >> 4;            // row-in-group 0..3
    const int dl   = (lane & 15) * 8;      // d-chunk base
    const int r    = gw * 4 + sub;
    const float* src; int* dst; int row;
    if (r < NROWS) { src = qg; dst = qh; row = r; }
    else           { src = kg; dst = kh; row = r - NROWS; }

    const float* x = src + (size_t)row * DIM + dl;
    float xv[8];
    {
        float4 f0 = *(const float4*)x;
        float4 f1 = *(const float4*)(x + 4);
        xv[0]=f0.x; xv[1]=f0.y; xv[2]=f0.z; xv[3]=f0.w;
        xv[4]=f1.x; xv[5]=f1.y; xv[6]=f1.z; xv[7]=f1.w;
    }
    float pj[56];
    #pragma unroll
    for (int i = 0; i < 14; ++i)
        *(float4*)&pj[i*4] = *(const float4*)(proj + dl*7 + i*4);

    float a[7] = {0.f,0.f,0.f,0.f,0.f,0.f,0.f};
    #pragma unroll
    for (int d = 0; d < 8; ++d)
        #pragma unroll
        for (int p = 0; p < 7; ++p) a[p] = fmaf(xv[d], pj[d*7+p], a[p]);

    #pragma unroll
    for (int off = 1; off < 16; off <<= 1)
        #pragma unroll
        for (int p = 0; p < 7; ++p) a[p] += __shfl_xor(a[p], off, 64);

    if ((lane & 15) == 0) {
        int code = 0;
        if (a[0] > 0.f) code |= 1;  if (a[1] > 0.f) code |= 2;
        if (a[2] > 0.f) code |= 4;  if (a[3] > 0.f) code |= 8;
        if (a[4] > 0.f) code |= 16; if (a[5] > 0.f) code |= 32;
        if (a[6] > 0.f) code |= 64;
        dst[row] = code ^ (code >> 1);
    }
}

// ---------------- parallel stable counting sort per (b,h)
__global__ __launch_bounds__(256) void sort_kernel(const int* __restrict__ qh,
                                                   int* __restrict__ sidx, int* __restrict__ qhs)
{
    __shared__ __align__(16) unsigned short cnt[128][260];
    __shared__ int startv[128];
    const int bh = blockIdx.x;
    const int t  = threadIdx.x;
    const int base = bh*SEQ;

    // vectorized zeroing: 128*260 = 33280 shorts = 4160 short8s
    {
        const short8 z8 = {0,0,0,0,0,0,0,0};
        for (int i = t; i < 4160; i += 256) ((short8*)cnt)[i] = z8;
    }
    __syncthreads();

    int hv[8];
    {
        int4 a = *(const int4*)(qh + base + t*8);
        int4 b = *(const int4*)(qh + base + t*8 + 4);
        hv[0]=a.x; hv[1]=a.y; hv[2]=a.z; hv[3]=a.w;
        hv[4]=b.x; hv[5]=b.y; hv[6]=b.z; hv[7]=b.w;
    }
    #pragma unroll
    for (int i = 0; i < 8; ++i) cnt[hv[i]][t]++;
    __syncthreads();

    // per-value exclusive column prefix: wave wv handles values wv, wv+4, ...
    const int wv = t >> 6, l = t & 63;
    #pragma unroll 1
    for (int v = wv; v < 128; v += 4) {
        ushort4 cc = *(const ushort4*)&cnt[v][4*l];
        unsigned c0 = cc.x, c1 = cc.y, c2 = cc.z, c3 = cc.w;
        unsigned s01 = c0 + c1;
        unsigned s = s01 + c2 + c3;
        unsigned inc = s;
        #pragma unroll
        for (int off = 1; off < 64; off <<= 1) {
            unsigned o = __shfl_up(inc, off, 64);
            if (l >= off) inc += o;
        }
        unsigned ex = inc - s;
        ushort4 wb;
        wb.x = (unsigned short)ex;
        wb.y = (unsigned short)(ex + c0);
        wb.z = (unsigned short)(ex + s01);
        wb.w = (unsigned short)(ex + s01 + c2);
        *(ushort4*)&cnt[v][4*l] = wb;
        if (l == 63) cnt[v][256] = (unsigned short)inc;   // total count of v
    }
    __syncthreads();

    // exclusive prefix over the 128 per-value totals (wave 0, 2 values/lane)
    if (t < 64) {
        int a0 = cnt[2*t][256], a1 = cnt[2*t+1][256];
        int s2 = a0 + a1, inc = s2;
        #pragma unroll
        for (int off = 1; off < 64; off <<= 1) {
            int o = __shfl_up(inc, off, 64);
            if (t >= off) inc += o;
        }
        int ex = inc - s2;
        startv[2*t]   = ex;
        startv[2*t+1] = ex + a0;
    }
    __syncthreads();

    #pragma unroll
    for (int i = 0; i < 8; ++i) {
        const int v = hv[i];
        int prior = 0;
        #pragma unroll
        for (int j = 0; j < 8; ++j) if (j < i && hv[j] == v) ++prior;
        const int rank = startv[v] + (int)cnt[v][t] + prior;
        sidx[base + rank] = t*8 + i;
        qhs[base + rank]  = v;
    }
}

// ---------------- prep: K -> bf16 row-major; V -> bf16 transposed [h][d][key]
__global__ __launch_bounds__(256) void prep_kernel(const float* __restrict__ kg,
                                                   const float* __restrict__ vg,
                                                   unsigned short* __restrict__ kbf,
                                                   unsigned short* __restrict__ vtg)
{
    __shared__ unsigned short T[128][72];
    const int t  = threadIdx.x;
    const int h  = blockIdx.x >> 5;
    const int sl = blockIdx.x & 31;
    const size_t base = ((size_t)h*SEQ + sl*64) * DIM;

    #pragma unroll
    for (int i = 0; i < 8; ++i) {
        const float4 f = *(const float4*)(kg + base + ((size_t)i*256 + t)*4);
        uint2 pk; pk.x = pack_bf16(f.x, f.y); pk.y = pack_bf16(f.z, f.w);
        *(uint2*)(kbf + base + ((size_t)i*256 + t)*4) = pk;
    }

    const int kk = t & 63, seg = t >> 6;
    #pragma unroll
    for (int i = 0; i < 8; ++i) {
        float4 f = *(const float4*)(vg + base + (size_t)kk*DIM + seg*32 + i*4);
        T[seg*32 + i*4 + 0][kk] = f2bf(f.x);
        T[seg*32 + i*4 + 1][kk] = f2bf(f.y);
        T[seg*32 + i*4 + 2][kk] = f2bf(f.z);
        T[seg*32 + i*4 + 3][kk] = f2bf(f.w);
    }
    __syncthreads();
    const int r = t >> 1, hf = t & 1;
    unsigned short* dst = vtg + ((size_t)h*DIM + r)*SEQ + sl*64 + hf*32;
    #pragma unroll
    for (int i = 0; i < 4; ++i)
        *(short8*)(dst + i*8) = *(const short8*)&T[r][hf*32 + i*8];
}

// ---------------- dense flash attention + FUSED critical attention / MSE loss.
// Dense body = round-0 proven structure verbatim (89.8 us: koff/voff XOR layout, plain
// __syncthreads double-buffer, 512 blocks = 2/CU, no setprio -- r6 showed setprio
// neutral-to-negative). After the K-loop, each wave runs the crit attention for ITS
// 32-block: dense block (head,qblk) wave w owns output rows head*2048+(qblk*4+w)*32+l31,
// which is exactly crit block nb = head*64+qblk*4+w. MSE uses the IN-REGISTER dense
// output -- the separate crit_attn dispatch, its 32MB outg re-read, and one launch
// disappear. Crit PV restructured mt-outer (one o2 float16 live) to cap VGPR.
__global__ __launch_bounds__(256, 2) void dense_attn_mfma(
    const unsigned short* __restrict__ kbf, const unsigned short* __restrict__ vtg,
    const float* __restrict__ qg, float* __restrict__ outg,
    const int* __restrict__ sidx, const int* __restrict__ kh,
    const int* __restrict__ qhs, float* __restrict__ lossp)
{
    __shared__ __align__(16) unsigned short KbF[2*8192];   // [buf][key(64) x d(128)]
    __shared__ __align__(16) unsigned short VbF[2*8192];   // [buf][d(128) x key(64)]
    __shared__ float wsum[4];

    const int t    = threadIdx.x;
    const int lane = t & 63;
    const int w    = t >> 6;
    const int q5   = lane >> 5;
    const int l31  = lane & 31;
    const int e    = l31 & 7;

    const int b    = blockIdx.x;      // 512 blocks
    const int slot = b >> 3;
    const int head = (b & 7) * 4 + (slot >> 4);   // XCD swizzle
    const int qblk = slot & 15;

    const float* Qg = qg + ((size_t)head*SEQ + qblk*128 + w*32) * DIM;
    const unsigned short* Kh = kbf + (size_t)head*SEQ*DIM;
    const unsigned short* Vh = vtg + (size_t)head*DIM*SEQ;

    // ---- kt-invariant LDS read offsets (shorts), swizzle baked in
    int koff[8], voff[4];
    #pragma unroll
    for (int ch = 0; ch < 8; ++ch) koff[ch] = l31*128 + (((2*ch + q5) ^ e) * 8);
    #pragma unroll
    for (int u = 0; u < 4; ++u)    voff[u]  = l31*64  + ((((u>>1)*4 + (u&1)*2 + q5) ^ e) * 8);

    // ---- kt-invariant staging pointers (advance by const per tile)
    const unsigned short* kgp[4]; unsigned short* kls[4];
    const unsigned short* vgp[4]; unsigned short* vls[4];
    #pragma unroll
    for (int i = 0; i < 4; ++i) {
        const int j = w*4 + i;
        const int r = j*4 + (lane >> 4);
        const int u = (lane & 15) ^ (r & 7);
        kgp[i] = Kh + r*DIM + u*8;            // += 8192 per tile
        kls[i] = KbF + j*512;
        const int d = j*8 + (lane >> 3);
        const int u2 = (lane & 7) ^ (d & 7);
        vgp[i] = Vh + (size_t)d*SEQ + u2*8;   // += 64 per tile
        vls[i] = VbF + j*512;
    }

    // ---- Q frags (B-operand), pre-scaled by SCALE*log2e
    union FR { unsigned u[4]; short8 s; };
    short8 Qf[8];
    #pragma unroll
    for (int ch = 0; ch < 8; ++ch) {
        const float* p = Qg + (size_t)l31*DIM + ch*16 + q5*8;
        float4 f0 = *(const float4*)p;
        float4 f1 = *(const float4*)(p + 4);
        FR fr;
        fr.u[0] = pack_bf16(f0.x*QSC, f0.y*QSC);
        fr.u[1] = pack_bf16(f0.z*QSC, f0.w*QSC);
        fr.u[2] = pack_bf16(f1.x*QSC, f1.y*QSC);
        fr.u[3] = pack_bf16(f1.z*QSC, f1.w*QSC);
        Qf[ch] = fr.s;
    }

    float16 o[4];
    #pragma unroll
    for (int mt = 0; mt < 4; ++mt)
        #pragma unroll
        for (int r = 0; r < 16; ++r) o[mt][r] = 0.f;
    float lsum = 0.f;

    auto stage = [&](const int buf) {
        #pragma unroll
        for (int i = 0; i < 4; ++i) gl_lds16(kgp[i], kls[i] + buf*8192);
        #pragma unroll
        for (int i = 0; i < 4; ++i) gl_lds16(vgp[i], vls[i] + buf*8192);
        #pragma unroll
        for (int i = 0; i < 4; ++i) { kgp[i] += 8192; vgp[i] += 64; }
    };

    auto body = [&](const int buf) {
        #pragma unroll
        for (int s = 0; s < 2; ++s) {
            float16 sv;
            #pragma unroll
            for (int r = 0; r < 16; ++r) sv[r] = 0.f;
            #pragma unroll
            for (int ch = 0; ch < 8; ++ch) {
                short8 kf = *(const short8*)&KbF[buf*8192 + s*4096 + koff[ch]];
                sv = __builtin_amdgcn_mfma_f32_32x32x16_bf16(kf, Qf[ch], sv, 0, 0, 0);
            }
            unsigned pk[8];
            #pragma unroll
            for (int rp = 0; rp < 8; ++rp) {
                float p0 = __builtin_amdgcn_exp2f(sv[2*rp]);
                float p1 = __builtin_amdgcn_exp2f(sv[2*rp+1]);
                lsum += p0 + p1;
                pk[rp] = pack_bf16(p0, p1);
            }
            unsigned e0 = __shfl_xor(q5 ? pk[0] : pk[2], 32, 64);
            unsigned e1 = __shfl_xor(q5 ? pk[1] : pk[3], 32, 64);
            unsigned e2 = __shfl_xor(q5 ? pk[4] : pk[6], 32, 64);
            unsigned e3 = __shfl_xor(q5 ? pk[5] : pk[7], 32, 64);
            FR c0, c1;
            if (q5 == 0) {
                c0.u[0]=pk[0]; c0.u[1]=pk[1]; c0.u[2]=e0;    c0.u[3]=e1;
                c1.u[0]=pk[4]; c1.u[1]=pk[5]; c1.u[2]=e2;    c1.u[3]=e3;
            } else {
                c0.u[0]=e0;    c0.u[1]=e1;    c0.u[2]=pk[2]; c0.u[3]=pk[3];
                c1.u[0]=e2;    c1.u[1]=e3;    c1.u[2]=pk[6]; c1.u[3]=pk[7];
            }
            #pragma unroll
            for (int c = 0; c < 2; ++c) {
                short8 pf = c ? c1.s : c0.s;
                #pragma unroll
                for (int mt = 0; mt < 4; ++mt) {
                    short8 vf = *(const short8*)&VbF[buf*8192 + mt*2048 + voff[s*2 + c]];
                    o[mt] = __builtin_amdgcn_mfma_f32_32x32x16_bf16(vf, pf, o[mt], 0, 0, 0);
                }
            }
        }
    };

    stage(0);                               // tile 0 -> buf0
    #pragma unroll 1
    for (int kt2 = 0; kt2 < 16; ++kt2) {
        __syncthreads();                    // buf0 ready (DMA drained by barrier)
        stage(1);                           // tile 2*kt2+1 -> buf1
        body(0);                            // consume tile 2*kt2
        __syncthreads();                    // buf1 ready; buf0 reads done
        if (kt2 < 15) stage(0);             // tile 2*kt2+2 -> buf0
        body(1);                            // consume tile 2*kt2+1
    }

    const float l = lsum + __shfl_xor(lsum, 32, 64);
    const float inv = 1.f / l;
    float* orow = outg + ((size_t)head*SEQ + qblk*128 + w*32 + l31) * DIM;
    #pragma unroll
    for (int mt = 0; mt < 4; ++mt)
        #pragma unroll
        for (int rg = 0; rg < 4; ++rg) {
            const int d0 = mt*32 + rg*8 + q5*4;
            float4 ov;
            ov.x = o[mt][rg*4+0]*inv; ov.y = o[mt][rg*4+1]*inv;
            ov.z = o[mt][rg*4+2]*inv; ov.w = o[mt][rg*4+3]*inv;
            *(float4*)(orow + d0) = ov;
        }

    // ================= fused critical attention (this wave's 32-block) =============
    const int nb = head*64 + qblk*4 + w;

    // keep = 1 iff zero hash matches in this 32-block
    const int khv = kh[nb*32 + l31];
    const int qhv = qhs[nb*32 + l31];
    const unsigned long long mm = __ballot(khv == qhv);
    const float kp = ((mm & 0xffffffffull) == 0ull) ? 1.0f : 0.0f;

    const int qrow = sidx[head*SEQ + (qblk*4 + w)*32 + l31];

    // Q frags, gathered (sorted) rows
    short8 Qf2[8];
    const float* Qg2 = qg + ((size_t)head*SEQ + qrow) * DIM;
    #pragma unroll
    for (int ch = 0; ch < 8; ++ch) {
        const float* p = Qg2 + ch*16 + q5*8;
        float4 f0 = *(const float4*)p;
        float4 f1 = *(const float4*)(p + 4);
        FR fr;
        fr.u[0] = pack_bf16(f0.x*QSC, f0.y*QSC);
        fr.u[1] = pack_bf16(f0.z*QSC, f0.w*QSC);
        fr.u[2] = pack_bf16(f1.x*QSC, f1.y*QSC);
        fr.u[3] = pack_bf16(f1.z*QSC, f1.w*QSC);
        Qf2[ch] = fr.s;
    }

    // QK^T over 32 keys (2 accumulator chains), K direct from L2/L3-resident kbf
    const unsigned short* Kb = kbf + (size_t)(nb*32) * DIM;
    float16 sv, sw;
    #pragma unroll
    for (int r = 0; r < 16; ++r) { sv[r] = 0.f; sw[r] = 0.f; }
    #pragma unroll
    for (int ch = 0; ch < 4; ++ch) {
        short8 kf = *(const short8*)(Kb + (size_t)l31*DIM + ch*16 + q5*8);
        sv = __builtin_amdgcn_mfma_f32_32x32x16_bf16(kf, Qf2[ch], sv, 0, 0, 0);
        short8 kg2 = *(const short8*)(Kb + (size_t)l31*DIM + (ch+4)*16 + q5*8);
        sw = __builtin_amdgcn_mfma_f32_32x32x16_bf16(kg2, Qf2[ch+4], sw, 0, 0, 0);
    }

    // softmax over 32 keys (kp==0 -> exp2(0)=1 -> uniform P, matches reference)
    float lsum2 = 0.f;
    unsigned pk2[8];
    #pragma unroll
    for (int rp = 0; rp < 8; ++rp) {
        float p0 = __builtin_amdgcn_exp2f((sv[2*rp]   + sw[2*rp])   * kp);
        float p1 = __builtin_amdgcn_exp2f((sv[2*rp+1] + sw[2*rp+1]) * kp);
        lsum2 += p0 + p1;
        pk2[rp] = pack_bf16(p0, p1);
    }
    unsigned f0 = __shfl_xor(q5 ? pk2[0] : pk2[2], 32, 64);
    unsigned f1 = __shfl_xor(q5 ? pk2[1] : pk2[3], 32, 64);
    unsigned f2 = __shfl_xor(q5 ? pk2[4] : pk2[6], 32, 64);
    unsigned f3 = __shfl_xor(q5 ? pk2[5] : pk2[7], 32, 64);
    FR d0c, d1c;
    if (q5 == 0) {
        d0c.u[0]=pk2[0]; d0c.u[1]=pk2[1]; d0c.u[2]=f0;     d0c.u[3]=f1;
        d1c.u[0]=pk2[4]; d1c.u[1]=pk2[5]; d1c.u[2]=f2;     d1c.u[3]=f3;
    } else {
        d0c.u[0]=f0;     d0c.u[1]=f1;     d0c.u[2]=pk2[2]; d0c.u[3]=pk2[3];
        d1c.u[0]=f2;     d1c.u[1]=f3;     d1c.u[2]=pk2[6]; d1c.u[3]=pk2[7];
    }
    const float ltot2 = lsum2 + __shfl_xor(lsum2, 32, 64);
    const float inv2  = 1.f / ltot2;

    // PV (mt-outer: one o2 live at a time) + in-register MSE vs dense output
    const unsigned short* Vb = vtg + (size_t)head*DIM*SEQ + (size_t)(qblk*4 + w)*32;
    float sq = 0.f;
    #pragma unroll
    for (int mt = 0; mt < 4; ++mt) {
        float16 o2;
        #pragma unroll
        for (int r = 0; r < 16; ++r) o2[r] = 0.f;
        #pragma unroll
        for (int c = 0; c < 2; ++c) {
            short8 pf = c ? d1c.s : d0c.s;
            short8 vf = *(const short8*)(Vb + (size_t)(mt*32 + l31)*SEQ + c*16 + q5*8);
            o2 = __builtin_amdgcn_mfma_f32_32x32x16_bf16(vf, pf, o2, 0, 0, 0);
        }
        #pragma unroll
        for (int r = 0; r < 16; ++r) {
            float d = o2[r]*inv2 - o[mt][r]*inv;
            sq += d*d;
        }
    }
    #pragma unroll
    for (int off = 32; off > 0; off >>= 1) sq += __shfl_down(sq, off, 64);
    if (lane == 0) wsum[w] = sq;
    __syncthreads();
    if (t == 0) atomicAdd(lossp, (wsum[0]+wsum[1]+wsum[2]+wsum[3]) * (1.0f/8388608.0f));
}

extern "C" void kernel_launch(void* const* d_in, const int* in_sizes, int n_in,
                              void* d_out, int out_size, void* d_ws, size_t ws_size,
                              hipStream_t stream)
{
    const float* q    = (const float*)d_in[0];
    const float* k    = (const float*)d_in[1];
    const float* v    = (const float*)d_in[2];
    const float* proj = (const float*)d_in[3];
    float* out   = (float*)d_out;
    float* lossp = out + (out_size - 1);

    int* qh   = (int*)d_ws;
    int* kh   = qh + NROWS;
    int* sidx = kh + NROWS;
    int* qhs  = sidx + NROWS;
    unsigned short* kbf = (unsigned short*)(qhs + NROWS);    // 16 MB
    unsigned short* vtg = kbf + (size_t)NROWS*DIM;           // 16 MB

    hipMemsetAsync(lossp, 0, sizeof(float), stream);
    prep_kernel<<<NBH*32, 256, 0, stream>>>(k, v, kbf, vtg);
    hash_kernel<<<(2*NROWS)/16, 256, 0, stream>>>(q, k, proj, qh, kh);
    sort_kernel<<<NBH, 256, 0, stream>>>(qh, sidx, qhs);
    dense_attn_mfma<<<512, 256, 0, stream>>>(kbf, vtg, q, out, sidx, kh, qhs, lossp);
}